// Round 2
// baseline (217.858 us; speedup 1.0000x reference)
//
#include <hip/hip_runtime.h>
#include <stdint.h>

#define Bdim 4
#define Ldim 512
#define Hdim 768
#define Edim 10
#define Rdim 10

typedef __attribute__((ext_vector_type(8))) short short8;
typedef __attribute__((ext_vector_type(4))) float floatx4;

__device__ __forceinline__ unsigned short f2bf(float x) {
    unsigned int u = __float_as_uint(x);
    unsigned int r = (u + 0x7fffu + ((u >> 16) & 1u)) >> 16;
    return (unsigned short)r;
}
__device__ __forceinline__ float bf2f(unsigned short u) {
    return __uint_as_float(((unsigned int)u) << 16);
}

#define GLOAD_LDS16(g, l)                                                      \
    __builtin_amdgcn_global_load_lds(                                          \
        (const __attribute__((address_space(1))) void*)(g),                    \
        (__attribute__((address_space(3))) void*)(l), 16, 0, 0)

// ---------------- f32 -> bf16 conversion (vectorized) ----------------
__global__ void k_cvt(const float* __restrict__ src,
                      unsigned short* __restrict__ dst, int n4) {
    int i = blockIdx.x * blockDim.x + threadIdx.x;
    int stride = gridDim.x * blockDim.x;
    for (; i < n4; i += stride) {
        float4 v = reinterpret_cast<const float4*>(src)[i];
        ushort4 o;
        o.x = f2bf(v.x); o.y = f2bf(v.y); o.z = f2bf(v.z); o.w = f2bf(v.w);
        reinterpret_cast<ushort4*>(dst)[i] = o;
    }
}

// ---------------- core: C[128x128] += A(row-major) x B(row-major)^T ----------
// C[m,n] = sum_k A[m,k] * B[n,k].  BK=32, 4 waves, m97 structure.
__device__ __forceinline__ void gemm_bt_core(
    const unsigned short* __restrict__ A, int lda,
    const unsigned short* __restrict__ Bm, int ldb,
    int K,
    unsigned short* lA, unsigned short* lB,
    floatx4 acc[4][4])
{
    const int tid  = threadIdx.x;
    const int lane = tid & 63;
    const int wave = tid >> 6;
    const int wr = wave >> 1;
    const int wc = wave & 1;
    const int srow = tid >> 2;          // 0..63 (staging row within half-tile)
    const int skk  = (tid & 3) << 3;    // 0,8,16,24 (k offset, 8 bf16 = 16B)

    const int frow = lane & 15;
    const int fko  = (lane >> 4) << 3;  // k offset for fragment read

    for (int k0 = 0; k0 < K; k0 += 32) {
        const unsigned short* ga0 = A  + (size_t)srow * lda + k0 + skk;
        const unsigned short* ga1 = ga0 + (size_t)64 * lda;
        const unsigned short* gb0 = Bm + (size_t)srow * ldb + k0 + skk;
        const unsigned short* gb1 = gb0 + (size_t)64 * ldb;
        GLOAD_LDS16(ga0, lA + tid * 8);
        GLOAD_LDS16(ga1, lA + 2048 + tid * 8);
        GLOAD_LDS16(gb0, lB + tid * 8);
        GLOAD_LDS16(gb1, lB + 2048 + tid * 8);
        __syncthreads();   // compiler emits vmcnt(0) drain before barrier

        short8 af[4], bfr[4];
        #pragma unroll
        for (int mi = 0; mi < 4; ++mi)
            af[mi] = *reinterpret_cast<const short8*>(
                lA + (wr * 64 + mi * 16 + frow) * 32 + fko);
        #pragma unroll
        for (int ni = 0; ni < 4; ++ni)
            bfr[ni] = *reinterpret_cast<const short8*>(
                lB + (wc * 64 + ni * 16 + frow) * 32 + fko);
        #pragma unroll
        for (int mi = 0; mi < 4; ++mi)
            #pragma unroll
            for (int ni = 0; ni < 4; ++ni)
                acc[mi][ni] = __builtin_amdgcn_mfma_f32_16x16x32_bf16(
                    af[mi], bfr[ni], acc[mi][ni], 0, 0, 0);
        __syncthreads();   // protect LDS from next-iter staging
    }
}

// ---------------- GEMM1: hp = relu(h @ Wproj^T + b) -> bf16 ----------------
__global__ __launch_bounds__(256) void k_gemm_proj(
    const unsigned short* __restrict__ hA,
    const unsigned short* __restrict__ Wp,
    const float* __restrict__ bproj,
    unsigned short* __restrict__ hp)
{
    __shared__ unsigned short lA[128 * 32];
    __shared__ unsigned short lB[128 * 32];
    const int m0 = blockIdx.x * 128;
    const int n0 = blockIdx.y * 128;
    floatx4 acc[4][4];
    #pragma unroll
    for (int i = 0; i < 4; ++i)
        #pragma unroll
        for (int j = 0; j < 4; ++j)
            acc[i][j] = (floatx4){0.f, 0.f, 0.f, 0.f};

    gemm_bt_core(hA + (size_t)m0 * Hdim, Hdim,
                 Wp + (size_t)n0 * Hdim, Hdim, Hdim, lA, lB, acc);

    const int tid = threadIdx.x, lane = tid & 63, wave = tid >> 6;
    const int wr = wave >> 1, wc = wave & 1;
    const int cl = lane & 15, rh = (lane >> 4) * 4;
    #pragma unroll
    for (int mi = 0; mi < 4; ++mi)
        #pragma unroll
        for (int ni = 0; ni < 4; ++ni)
            #pragma unroll
            for (int j = 0; j < 4; ++j) {
                int r = m0 + wr * 64 + mi * 16 + rh + j;
                int c = n0 + wc * 64 + ni * 16 + cl;
                float v = acc[mi][ni][j] + bproj[c];
                hp[(size_t)r * Hdim + c] = f2bf(fmaxf(v, 0.0f));
            }
}

// ---------------- GEMM2: T[m, r*768+h] = hp @ Wbil^T -> bf16 ---------------
__global__ __launch_bounds__(256) void k_gemm_t(
    const unsigned short* __restrict__ hp,
    const unsigned short* __restrict__ Wb,
    unsigned short* __restrict__ T)
{
    __shared__ unsigned short lA[128 * 32];
    __shared__ unsigned short lB[128 * 32];
    const int m0 = blockIdx.x * 128;
    const int n0 = blockIdx.y * 128;   // over R*H = 7680
    floatx4 acc[4][4];
    #pragma unroll
    for (int i = 0; i < 4; ++i)
        #pragma unroll
        for (int j = 0; j < 4; ++j)
            acc[i][j] = (floatx4){0.f, 0.f, 0.f, 0.f};

    gemm_bt_core(hp + (size_t)m0 * Hdim, Hdim,
                 Wb + (size_t)n0 * Hdim, Hdim, Hdim, lA, lB, acc);

    const int tid = threadIdx.x, lane = tid & 63, wave = tid >> 6;
    const int wr = wave >> 1, wc = wave & 1;
    const int cl = lane & 15, rh = (lane >> 4) * 4;
    #pragma unroll
    for (int mi = 0; mi < 4; ++mi)
        #pragma unroll
        for (int ni = 0; ni < 4; ++ni)
            #pragma unroll
            for (int j = 0; j < 4; ++j) {
                int r = m0 + wr * 64 + mi * 16 + rh + j;
                int c = n0 + wc * 64 + ni * 16 + cl;
                T[(size_t)r * (Rdim * Hdim) + c] = f2bf(acc[mi][ni][j]);
            }
}

// ---------------- GEMM3: rel[b,l,m,r] = hp_b @ T_{b,r}^T + bbil[r] ---------
__global__ __launch_bounds__(256) void k_gemm_rel(
    const unsigned short* __restrict__ hp,
    const unsigned short* __restrict__ T,
    const float* __restrict__ bbil,
    float* __restrict__ rel)
{
    __shared__ unsigned short lA[128 * 32];
    __shared__ unsigned short lB[128 * 32];
    const int bz = blockIdx.z;          // 0..39
    const int b = bz / Rdim, r = bz % Rdim;
    const int m0 = blockIdx.x * 128;    // l
    const int n0 = blockIdx.y * 128;    // m
    floatx4 acc[4][4];
    #pragma unroll
    for (int i = 0; i < 4; ++i)
        #pragma unroll
        for (int j = 0; j < 4; ++j)
            acc[i][j] = (floatx4){0.f, 0.f, 0.f, 0.f};

    const unsigned short* Ab = hp + ((size_t)b * Ldim + m0) * Hdim;
    const unsigned short* Bb = T + ((size_t)b * Ldim + n0) * (Rdim * Hdim)
                                 + (size_t)r * Hdim;
    gemm_bt_core(Ab, Hdim, Bb, Rdim * Hdim, Hdim, lA, lB, acc);

    const float bias = bbil[r];
    const int tid = threadIdx.x, lane = tid & 63, wave = tid >> 6;
    const int wr = wave >> 1, wc = wave & 1;
    const int cl = lane & 15, rh = (lane >> 4) * 4;
    #pragma unroll
    for (int mi = 0; mi < 4; ++mi)
        #pragma unroll
        for (int ni = 0; ni < 4; ++ni)
            #pragma unroll
            for (int j = 0; j < 4; ++j) {
                int lrow = m0 + wr * 64 + mi * 16 + rh + j;
                int mcol = n0 + wc * 64 + ni * 16 + cl;
                rel[(((size_t)b * Ldim + lrow) * Ldim + mcol) * Rdim + r] =
                    acc[mi][ni][j] + bias;
            }
}

// ---------------- ent_logits: wave-per-row, 10 dots of length 768 ----------
__global__ __launch_bounds__(256) void k_ent(
    const unsigned short* __restrict__ hp,
    const unsigned short* __restrict__ We,
    const float* __restrict__ bent,
    float* __restrict__ out)
{
    const int gw = (blockIdx.x * blockDim.x + threadIdx.x) >> 6;  // wave id
    const int lane = threadIdx.x & 63;
    if (gw >= Bdim * Ldim) return;
    const unsigned short* row = hp + (size_t)gw * Hdim;
    float hv[12];
    #pragma unroll
    for (int j = 0; j < 12; ++j) hv[j] = bf2f(row[lane + j * 64]);
    #pragma unroll
    for (int e = 0; e < Edim; ++e) {
        const unsigned short* wrow = We + e * Hdim;
        float s = 0.f;
        #pragma unroll
        for (int j = 0; j < 12; ++j) s += hv[j] * bf2f(wrow[lane + j * 64]);
        #pragma unroll
        for (int off = 32; off >= 1; off >>= 1) s += __shfl_xor(s, off);
        if (lane == 0) out[(size_t)gw * Edim + e] = s + bent[e];
    }
}

extern "C" void kernel_launch(void* const* d_in, const int* in_sizes, int n_in,
                              void* d_out, int out_size, void* d_ws, size_t ws_size,
                              hipStream_t stream)
{
    const float* h     = (const float*)d_in[0];
    const float* Wproj = (const float*)d_in[1];
    const float* bproj = (const float*)d_in[2];
    const float* Went  = (const float*)d_in[3];
    const float* bent  = (const float*)d_in[4];
    const float* Wbil  = (const float*)d_in[5];
    const float* bbil  = (const float*)d_in[6];

    float* out_ent = (float*)d_out;
    float* out_rel = (float*)d_out + (size_t)Bdim * Ldim * Edim;

    unsigned short* h_bf  = (unsigned short*)d_ws;
    unsigned short* Wp_bf = h_bf  + (size_t)2048 * Hdim;
    unsigned short* Wb_bf = Wp_bf + (size_t)Hdim * Hdim;
    unsigned short* We_bf = Wb_bf + (size_t)Rdim * Hdim * Hdim;
    unsigned short* hp_bf = We_bf + (size_t)Edim * Hdim;
    unsigned short* T_bf  = hp_bf + (size_t)2048 * Hdim;   // 2048 x 7680

    // conversions (grid-stride, float4)
    {
        int n4 = 2048 * Hdim / 4;
        k_cvt<<<dim3((n4 + 255) / 256 < 2048 ? (n4 + 255) / 256 : 2048), 256, 0, stream>>>(h, h_bf, n4);
        n4 = Hdim * Hdim / 4;
        k_cvt<<<dim3((n4 + 255) / 256 < 2048 ? (n4 + 255) / 256 : 2048), 256, 0, stream>>>(Wproj, Wp_bf, n4);
        n4 = Rdim * Hdim * Hdim / 4;
        k_cvt<<<dim3(2048), 256, 0, stream>>>(Wbil, Wb_bf, n4);
        n4 = Edim * Hdim / 4;
        k_cvt<<<dim3((n4 + 255) / 256), 256, 0, stream>>>(Went, We_bf, n4);
    }

    // GEMM1: hp = relu(h @ Wproj^T + b)   (2048x768) * (768x768)
    k_gemm_proj<<<dim3(2048 / 128, Hdim / 128), 256, 0, stream>>>(h_bf, Wp_bf, bproj, hp_bf);

    // ent logits (needs hp)
    k_ent<<<dim3((Bdim * Ldim * 64) / 256), 256, 0, stream>>>(hp_bf, We_bf, bent, out_ent);

    // GEMM2: T = hp @ Wbil^T   (2048x768) * (768x7680)
    k_gemm_t<<<dim3(2048 / 128, (Rdim * Hdim) / 128), 256, 0, stream>>>(hp_bf, Wb_bf, T_bf);

    // GEMM3: rel = hp_b @ T_{b,r}^T + bbil[r]  (40 batches of 512x512x768)
    k_gemm_rel<<<dim3(Ldim / 128, Ldim / 128, Bdim * Rdim), 256, 0, stream>>>(hp_bf, T_bf, bbil, out_rel);
}

// Round 3
// 182.365 us; speedup vs baseline: 1.1946x; 1.1946x over previous
//
#include <hip/hip_runtime.h>
#include <stdint.h>

#define Bdim 4
#define Ldim 512
#define Hdim 768
#define Edim 10
#define Rdim 10

typedef __attribute__((ext_vector_type(8))) short short8;
typedef __attribute__((ext_vector_type(4))) float floatx4;

__device__ __forceinline__ unsigned short f2bf(float x) {
    unsigned int u = __float_as_uint(x);
    unsigned int r = (u + 0x7fffu + ((u >> 16) & 1u)) >> 16;
    return (unsigned short)r;
}
__device__ __forceinline__ float bf2f(unsigned short u) {
    return __uint_as_float(((unsigned int)u) << 16);
}

#define GLOAD_LDS16(g, l)                                                      \
    __builtin_amdgcn_global_load_lds(                                          \
        (const __attribute__((address_space(1))) void*)(g),                    \
        (__attribute__((address_space(3))) void*)(l), 16, 0, 0)

// ---------------- fused f32 -> bf16 conversion (4 segments) ----------------
__global__ void k_cvt4(const float* __restrict__ s0, unsigned short* __restrict__ d0, int n0,
                       const float* __restrict__ s1, unsigned short* __restrict__ d1, int n1,
                       const float* __restrict__ s2, unsigned short* __restrict__ d2, int n2,
                       const float* __restrict__ s3, unsigned short* __restrict__ d3, int n3) {
    int total = n0 + n1 + n2 + n3;   // in float4 units
    int i = blockIdx.x * blockDim.x + threadIdx.x;
    int stride = gridDim.x * blockDim.x;
    for (; i < total; i += stride) {
        const float* s; unsigned short* d; int j = i;
        if (j < n0) { s = s0; d = d0; }
        else { j -= n0;
            if (j < n1) { s = s1; d = d1; }
            else { j -= n1;
                if (j < n2) { s = s2; d = d2; }
                else { j -= n2; s = s3; d = d3; }
            }
        }
        float4 v = reinterpret_cast<const float4*>(s)[j];
        ushort4 o;
        o.x = f2bf(v.x); o.y = f2bf(v.y); o.z = f2bf(v.z); o.w = f2bf(v.w);
        reinterpret_cast<ushort4*>(d)[j] = o;
    }
}

// ------------- core: C[128x128] += A(rm) x B(rm)^T, BK=64, XOR-swizzled LDS -
// C[m,n] = sum_k A[m,k]*B[n,k].  LDS [128][64] bf16 per matrix (16KB each).
// Swizzle: physical 16B-slot p of row r holds logical k-chunk (p ^ (r&7)).
// Staging keeps the LDS dest LINEAR (global_load_lds requirement) and
// pre-swizzles the global source chunk; ds_read applies the same XOR.
__device__ __forceinline__ void gemm_bt_core64(
    const unsigned short* __restrict__ A, int lda,
    const unsigned short* __restrict__ Bm, int ldb,
    int K,
    unsigned short* lA, unsigned short* lB,
    floatx4 acc[4][4])
{
    const int tid  = threadIdx.x;
    const int lane = tid & 63;
    const int wave = tid >> 6;
    const int wr = wave >> 1;
    const int wc = wave & 1;

    // staging: each thread handles one 16B chunk; 256 threads cover 32 rows/instr
    const int srow   = tid >> 3;                  // 0..31
    const int sslot  = tid & 7;                   // physical slot (linear LDS dest)
    const int schunk = sslot ^ (srow & 7);        // pre-swizzled logical k-chunk
    const int skk    = schunk << 3;               // k element offset

    const int frow = lane & 15;
    const int fs   = lane >> 4;                   // 0..3 (base k-chunk)

    for (int k0 = 0; k0 < K; k0 += 64) {
        #pragma unroll
        for (int i = 0; i < 4; ++i) {
            GLOAD_LDS16(A  + (size_t)(srow + 32 * i) * lda + k0 + skk,
                        lA + (tid + 256 * i) * 8);
            GLOAD_LDS16(Bm + (size_t)(srow + 32 * i) * ldb + k0 + skk,
                        lB + (tid + 256 * i) * 8);
        }
        __syncthreads();   // vmcnt(0) drain emitted by compiler

        #pragma unroll
        for (int h = 0; h < 2; ++h) {
            short8 af[4], bfr[4];
            #pragma unroll
            for (int mi = 0; mi < 4; ++mi) {
                int row  = wr * 64 + mi * 16 + frow;
                int slot = (fs + 4 * h) ^ (row & 7);
                af[mi] = *reinterpret_cast<const short8*>(lA + row * 64 + slot * 8);
            }
            #pragma unroll
            for (int ni = 0; ni < 4; ++ni) {
                int row  = wc * 64 + ni * 16 + frow;
                int slot = (fs + 4 * h) ^ (row & 7);
                bfr[ni] = *reinterpret_cast<const short8*>(lB + row * 64 + slot * 8);
            }
            #pragma unroll
            for (int mi = 0; mi < 4; ++mi)
                #pragma unroll
                for (int ni = 0; ni < 4; ++ni)
                    acc[mi][ni] = __builtin_amdgcn_mfma_f32_16x16x32_bf16(
                        af[mi], bfr[ni], acc[mi][ni], 0, 0, 0);
        }
        __syncthreads();
    }
}

// bijective XCD remap of a linear block id (nwg must be %8==0 — all our grids are)
__device__ __forceinline__ int xcd_swz(int bid, int nwg) {
    int cpx = nwg >> 3;
    return (bid & 7) * cpx + (bid >> 3);
}

// ---------------- GEMM1: hp = relu(h @ Wproj^T + b) -> bf16 ----------------
__global__ __launch_bounds__(256) void k_gemm_proj(
    const unsigned short* __restrict__ hA,
    const unsigned short* __restrict__ Wp,
    const float* __restrict__ bproj,
    unsigned short* __restrict__ hp)
{
    __shared__ unsigned short lA[128 * 64];
    __shared__ unsigned short lB[128 * 64];
    int bid = xcd_swz(blockIdx.x + gridDim.x * blockIdx.y, gridDim.x * gridDim.y);
    const int m0 = (bid % gridDim.x) * 128;
    const int n0 = (bid / gridDim.x) * 128;
    floatx4 acc[4][4];
    #pragma unroll
    for (int i = 0; i < 4; ++i)
        #pragma unroll
        for (int j = 0; j < 4; ++j)
            acc[i][j] = (floatx4){0.f, 0.f, 0.f, 0.f};

    gemm_bt_core64(hA + (size_t)m0 * Hdim, Hdim,
                   Wp + (size_t)n0 * Hdim, Hdim, Hdim, lA, lB, acc);

    const int tid = threadIdx.x, lane = tid & 63, wave = tid >> 6;
    const int wr = wave >> 1, wc = wave & 1;
    const int cl = lane & 15, rh = (lane >> 4) * 4;
    #pragma unroll
    for (int mi = 0; mi < 4; ++mi)
        #pragma unroll
        for (int ni = 0; ni < 4; ++ni)
            #pragma unroll
            for (int j = 0; j < 4; ++j) {
                int r = m0 + wr * 64 + mi * 16 + rh + j;
                int c = n0 + wc * 64 + ni * 16 + cl;
                float v = acc[mi][ni][j] + bproj[c];
                hp[(size_t)r * Hdim + c] = f2bf(fmaxf(v, 0.0f));
            }
}

// ---------------- GEMM2: T[m, r*768+h] = hp @ Wbil^T -> bf16 ---------------
__global__ __launch_bounds__(256) void k_gemm_t(
    const unsigned short* __restrict__ hp,
    const unsigned short* __restrict__ Wb,
    unsigned short* __restrict__ T)
{
    __shared__ unsigned short lA[128 * 64];
    __shared__ unsigned short lB[128 * 64];
    int bid = xcd_swz(blockIdx.x + gridDim.x * blockIdx.y, gridDim.x * gridDim.y);
    const int m0 = (bid % gridDim.x) * 128;
    const int n0 = (bid / gridDim.x) * 128;   // over R*H = 7680
    floatx4 acc[4][4];
    #pragma unroll
    for (int i = 0; i < 4; ++i)
        #pragma unroll
        for (int j = 0; j < 4; ++j)
            acc[i][j] = (floatx4){0.f, 0.f, 0.f, 0.f};

    gemm_bt_core64(hp + (size_t)m0 * Hdim, Hdim,
                   Wb + (size_t)n0 * Hdim, Hdim, Hdim, lA, lB, acc);

    const int tid = threadIdx.x, lane = tid & 63, wave = tid >> 6;
    const int wr = wave >> 1, wc = wave & 1;
    const int cl = lane & 15, rh = (lane >> 4) * 4;
    #pragma unroll
    for (int mi = 0; mi < 4; ++mi)
        #pragma unroll
        for (int ni = 0; ni < 4; ++ni)
            #pragma unroll
            for (int j = 0; j < 4; ++j) {
                int r = m0 + wr * 64 + mi * 16 + rh + j;
                int c = n0 + wc * 64 + ni * 16 + cl;
                T[(size_t)r * (Rdim * Hdim) + c] = f2bf(acc[mi][ni][j]);
            }
}

// ------- GEMM3 (N-merged): rel[b,l,m*10+r] = hp_b @ T2_b^T + bbil[r] -------
// T2[b, m*10+r, k] is exactly T's memory layout; rel output is contiguous in
// the merged n = m*10+r axis -> fully coalesced fp32 stores.
__global__ __launch_bounds__(256) void k_gemm_rel(
    const unsigned short* __restrict__ hp,
    const unsigned short* __restrict__ T,
    const float* __restrict__ bbil,
    float* __restrict__ rel)
{
    __shared__ unsigned short lA[128 * 64];
    __shared__ unsigned short lB[128 * 64];
    // grid (4, 40, 4): swizzle over the whole 640-block grid
    int nwg = gridDim.x * gridDim.y * gridDim.z;
    int bid = xcd_swz(blockIdx.x + gridDim.x * (blockIdx.y + gridDim.y * blockIdx.z), nwg);
    const int bx = bid % gridDim.x;
    const int by = (bid / gridDim.x) % gridDim.y;
    const int b  = bid / (gridDim.x * gridDim.y);
    const int m0 = bx * 128;            // l
    const int n0 = by * 128;            // merged (m,r), 0..5120
    floatx4 acc[4][4];
    #pragma unroll
    for (int i = 0; i < 4; ++i)
        #pragma unroll
        for (int j = 0; j < 4; ++j)
            acc[i][j] = (floatx4){0.f, 0.f, 0.f, 0.f};

    const unsigned short* Ab = hp + ((size_t)b * Ldim + m0) * Hdim;
    const unsigned short* Bb = T + (size_t)b * Ldim * (Rdim * Hdim) + (size_t)n0 * Hdim;
    gemm_bt_core64(Ab, Hdim, Bb, Hdim, Hdim, lA, lB, acc);

    const int tid = threadIdx.x, lane = tid & 63, wave = tid >> 6;
    const int wr = wave >> 1, wc = wave & 1;
    const int cl = lane & 15, rh = (lane >> 4) * 4;
    #pragma unroll
    for (int mi = 0; mi < 4; ++mi)
        #pragma unroll
        for (int ni = 0; ni < 4; ++ni) {
            int n = n0 + wc * 64 + ni * 16 + cl;
            float bias = bbil[n % Rdim];
            #pragma unroll
            for (int j = 0; j < 4; ++j) {
                int lrow = m0 + wr * 64 + mi * 16 + rh + j;
                rel[((size_t)b * Ldim + lrow) * (Ldim * Rdim) + n] =
                    acc[mi][ni][j] + bias;
            }
        }
}

// ---------------- ent_logits: wave-per-row, 10 dots of length 768 ----------
__global__ __launch_bounds__(256) void k_ent(
    const unsigned short* __restrict__ hp,
    const unsigned short* __restrict__ We,
    const float* __restrict__ bent,
    float* __restrict__ out)
{
    const int gw = (blockIdx.x * blockDim.x + threadIdx.x) >> 6;  // wave id
    const int lane = threadIdx.x & 63;
    if (gw >= Bdim * Ldim) return;
    const unsigned short* row = hp + (size_t)gw * Hdim;
    float hv[12];
    #pragma unroll
    for (int j = 0; j < 12; ++j) hv[j] = bf2f(row[lane + j * 64]);
    #pragma unroll
    for (int e = 0; e < Edim; ++e) {
        const unsigned short* wrow = We + e * Hdim;
        float s = 0.f;
        #pragma unroll
        for (int j = 0; j < 12; ++j) s += hv[j] * bf2f(wrow[lane + j * 64]);
        #pragma unroll
        for (int off = 32; off >= 1; off >>= 1) s += __shfl_xor(s, off);
        if (lane == 0) out[(size_t)gw * Edim + e] = s + bent[e];
    }
}

extern "C" void kernel_launch(void* const* d_in, const int* in_sizes, int n_in,
                              void* d_out, int out_size, void* d_ws, size_t ws_size,
                              hipStream_t stream)
{
    const float* h     = (const float*)d_in[0];
    const float* Wproj = (const float*)d_in[1];
    const float* bproj = (const float*)d_in[2];
    const float* Went  = (const float*)d_in[3];
    const float* bent  = (const float*)d_in[4];
    const float* Wbil  = (const float*)d_in[5];
    const float* bbil  = (const float*)d_in[6];

    float* out_ent = (float*)d_out;
    float* out_rel = (float*)d_out + (size_t)Bdim * Ldim * Edim;

    unsigned short* h_bf  = (unsigned short*)d_ws;
    unsigned short* Wp_bf = h_bf  + (size_t)2048 * Hdim;
    unsigned short* Wb_bf = Wp_bf + (size_t)Hdim * Hdim;
    unsigned short* We_bf = Wb_bf + (size_t)Rdim * Hdim * Hdim;
    unsigned short* hp_bf = We_bf + (size_t)Edim * Hdim;
    unsigned short* T_bf  = hp_bf + (size_t)2048 * Hdim;   // 2048 x 7680

    // single fused conversion launch
    {
        int n0 = 2048 * Hdim / 4;
        int n1 = Hdim * Hdim / 4;
        int n2 = Rdim * Hdim * Hdim / 4;
        int n3 = Edim * Hdim / 4;
        k_cvt4<<<dim3(2048), 256, 0, stream>>>(h, h_bf, n0, Wproj, Wp_bf, n1,
                                               Wbil, Wb_bf, n2, Went, We_bf, n3);
    }

    // GEMM1: hp = relu(h @ Wproj^T + b)   (2048x768) * (768x768)
    k_gemm_proj<<<dim3(2048 / 128, Hdim / 128), 256, 0, stream>>>(h_bf, Wp_bf, bproj, hp_bf);

    // ent logits (needs hp)
    k_ent<<<dim3((Bdim * Ldim * 64) / 256), 256, 0, stream>>>(hp_bf, We_bf, bent, out_ent);

    // GEMM2: T = hp @ Wbil^T   (2048x768) * (768x7680)
    k_gemm_t<<<dim3(2048 / 128, (Rdim * Hdim) / 128), 256, 0, stream>>>(hp_bf, Wb_bf, T_bf);

    // GEMM3: rel (N-merged)  4 batches of (512 x 5120 x 768)
    k_gemm_rel<<<dim3(Ldim / 128, (Ldim * Rdim) / 128, Bdim), 256, 0, stream>>>(hp_bf, T_bf, bbil, out_rel);
}

// Round 4
// 182.341 us; speedup vs baseline: 1.1948x; 1.0001x over previous
//
#include <hip/hip_runtime.h>
#include <stdint.h>

#define Bdim 4
#define Ldim 512
#define Hdim 768
#define Edim 10
#define Rdim 10

typedef __attribute__((ext_vector_type(8))) short short8;
typedef __attribute__((ext_vector_type(4))) float floatx4;

__device__ __forceinline__ unsigned short f2bf(float x) {
    unsigned int u = __float_as_uint(x);
    unsigned int r = (u + 0x7fffu + ((u >> 16) & 1u)) >> 16;
    return (unsigned short)r;
}
__device__ __forceinline__ float bf2f(unsigned short u) {
    return __uint_as_float(((unsigned int)u) << 16);
}

#define GLOAD_LDS16(g, l)                                                      \
    __builtin_amdgcn_global_load_lds(                                          \
        (const __attribute__((address_space(1))) void*)(g),                    \
        (__attribute__((address_space(3))) void*)(l), 16, 0, 0)

// ---------------- fused f32 -> bf16 conversion (4 segments) ----------------
__global__ void k_cvt4(const float* __restrict__ s0, unsigned short* __restrict__ d0, int n0,
                       const float* __restrict__ s1, unsigned short* __restrict__ d1, int n1,
                       const float* __restrict__ s2, unsigned short* __restrict__ d2, int n2,
                       const float* __restrict__ s3, unsigned short* __restrict__ d3, int n3) {
    int total = n0 + n1 + n2 + n3;   // in float4 units
    int i = blockIdx.x * blockDim.x + threadIdx.x;
    int stride = gridDim.x * blockDim.x;
    for (; i < total; i += stride) {
        const float* s; unsigned short* d; int j = i;
        if (j < n0) { s = s0; d = d0; }
        else { j -= n0;
            if (j < n1) { s = s1; d = d1; }
            else { j -= n1;
                if (j < n2) { s = s2; d = d2; }
                else { j -= n2; s = s3; d = d3; }
            }
        }
        float4 v = reinterpret_cast<const float4*>(s)[j];
        ushort4 o;
        o.x = f2bf(v.x); o.y = f2bf(v.y); o.z = f2bf(v.z); o.w = f2bf(v.w);
        reinterpret_cast<ushort4*>(d)[j] = o;
    }
}

// ---- core: C[128x128] += A(rm) x B(rm)^T, BK=64, DOUBLE-BUFFERED 2-phase ---
// C[m,n] = sum_k A[m,k]*B[n,k].
// LDS: 2 buffers x [128][64] bf16 per matrix (lA, lB each 32KB; 64KB/block ->
// 2 blocks/CU). Per K-tile: issue next tile's 8 global_load_lds FIRST, then
// ds_read+MFMA on current buffer, then ONE __syncthreads() (its vmcnt(0)+
// lgkmcnt(0) drain is the single sync point: staged loads have the whole MFMA
// phase in flight).  XOR swizzle (slot ^= row&7): LDS dest stays linear,
// global source chunk pre-swizzled, ds_read applies the same XOR (rule #21).
__device__ __forceinline__ void gemm_bt_core64_db(
    const unsigned short* __restrict__ A, int lda,
    const unsigned short* __restrict__ Bm, int ldb,
    int K,
    unsigned short* lA, unsigned short* lB,
    floatx4 acc[4][4])
{
    const int tid  = threadIdx.x;
    const int lane = tid & 63;
    const int wave = tid >> 6;
    const int wr = wave >> 1;
    const int wc = wave & 1;

    // staging: each thread one 16B chunk; 4 instrs cover 128 rows per matrix
    const int srow   = tid >> 3;                  // 0..31
    const int schunk = (tid & 7) ^ (srow & 7);    // pre-swizzled logical k-chunk
    const int skk    = schunk << 3;               // k element offset

    const int frow = lane & 15;
    const int fs   = lane >> 4;                   // 0..3 (base k-chunk)

    // prologue: stage K-tile 0 into buffer 0
    #pragma unroll
    for (int i = 0; i < 4; ++i) {
        GLOAD_LDS16(A  + (size_t)(srow + 32 * i) * lda + skk,
                    lA + (tid + 256 * i) * 8);
        GLOAD_LDS16(Bm + (size_t)(srow + 32 * i) * ldb + skk,
                    lB + (tid + 256 * i) * 8);
    }
    __syncthreads();

    const int nt = K >> 6;
    int buf = 0;
    for (int kt = 0; kt < nt; ++kt) {
        // phase 1: issue next K-tile staging into buf^1 (loads fly under MFMA)
        if (kt + 1 < nt) {
            const int k0n = (kt + 1) << 6;
            unsigned short* dA = lA + (buf ^ 1) * 8192;
            unsigned short* dB = lB + (buf ^ 1) * 8192;
            #pragma unroll
            for (int i = 0; i < 4; ++i) {
                GLOAD_LDS16(A  + (size_t)(srow + 32 * i) * lda + k0n + skk,
                            dA + (tid + 256 * i) * 8);
                GLOAD_LDS16(Bm + (size_t)(srow + 32 * i) * ldb + k0n + skk,
                            dB + (tid + 256 * i) * 8);
            }
        }
        // phase 2: compute current buffer
        const unsigned short* sA = lA + buf * 8192;
        const unsigned short* sB = lB + buf * 8192;
        #pragma unroll
        for (int h = 0; h < 2; ++h) {
            short8 af[4], bfr[4];
            #pragma unroll
            for (int mi = 0; mi < 4; ++mi) {
                int row  = wr * 64 + mi * 16 + frow;
                int slot = (fs + 4 * h) ^ (row & 7);
                af[mi] = *reinterpret_cast<const short8*>(sA + row * 64 + slot * 8);
            }
            #pragma unroll
            for (int ni = 0; ni < 4; ++ni) {
                int row  = wc * 64 + ni * 16 + frow;
                int slot = (fs + 4 * h) ^ (row & 7);
                bfr[ni] = *reinterpret_cast<const short8*>(sB + row * 64 + slot * 8);
            }
            #pragma unroll
            for (int mi = 0; mi < 4; ++mi)
                #pragma unroll
                for (int ni = 0; ni < 4; ++ni)
                    acc[mi][ni] = __builtin_amdgcn_mfma_f32_16x16x32_bf16(
                        af[mi], bfr[ni], acc[mi][ni], 0, 0, 0);
        }
        // single sync per K-tile: drains vmcnt(0) (next tile landed) and
        // lgkmcnt, and ensures all waves are done reading buf before reuse.
        __syncthreads();
        buf ^= 1;
    }
}

// bijective XCD remap of a linear block id (all our grids are %8==0)
__device__ __forceinline__ int xcd_swz(int bid, int nwg) {
    int cpx = nwg >> 3;
    return (bid & 7) * cpx + (bid >> 3);
}

// ---------------- GEMM1: hp = relu(h @ Wproj^T + b) -> bf16 ----------------
__global__ __launch_bounds__(256) void k_gemm_proj(
    const unsigned short* __restrict__ hA,
    const unsigned short* __restrict__ Wp,
    const float* __restrict__ bproj,
    unsigned short* __restrict__ hp)
{
    __shared__ unsigned short lA[2 * 128 * 64];
    __shared__ unsigned short lB[2 * 128 * 64];
    int bid = xcd_swz(blockIdx.x + gridDim.x * blockIdx.y, gridDim.x * gridDim.y);
    const int m0 = (bid % gridDim.x) * 128;
    const int n0 = (bid / gridDim.x) * 128;
    floatx4 acc[4][4];
    #pragma unroll
    for (int i = 0; i < 4; ++i)
        #pragma unroll
        for (int j = 0; j < 4; ++j)
            acc[i][j] = (floatx4){0.f, 0.f, 0.f, 0.f};

    gemm_bt_core64_db(hA + (size_t)m0 * Hdim, Hdim,
                      Wp + (size_t)n0 * Hdim, Hdim, Hdim, lA, lB, acc);

    const int tid = threadIdx.x, lane = tid & 63, wave = tid >> 6;
    const int wr = wave >> 1, wc = wave & 1;
    const int cl = lane & 15, rh = (lane >> 4) * 4;
    #pragma unroll
    for (int mi = 0; mi < 4; ++mi)
        #pragma unroll
        for (int ni = 0; ni < 4; ++ni)
            #pragma unroll
            for (int j = 0; j < 4; ++j) {
                int r = m0 + wr * 64 + mi * 16 + rh + j;
                int c = n0 + wc * 64 + ni * 16 + cl;
                float v = acc[mi][ni][j] + bproj[c];
                hp[(size_t)r * Hdim + c] = f2bf(fmaxf(v, 0.0f));
            }
}

// ---------------- GEMM2: T[m, r*768+h] = hp @ Wbil^T -> bf16 ---------------
__global__ __launch_bounds__(256) void k_gemm_t(
    const unsigned short* __restrict__ hp,
    const unsigned short* __restrict__ Wb,
    unsigned short* __restrict__ T)
{
    __shared__ unsigned short lA[2 * 128 * 64];
    __shared__ unsigned short lB[2 * 128 * 64];
    int bid = xcd_swz(blockIdx.x + gridDim.x * blockIdx.y, gridDim.x * gridDim.y);
    const int m0 = (bid % gridDim.x) * 128;
    const int n0 = (bid / gridDim.x) * 128;   // over R*H = 7680
    floatx4 acc[4][4];
    #pragma unroll
    for (int i = 0; i < 4; ++i)
        #pragma unroll
        for (int j = 0; j < 4; ++j)
            acc[i][j] = (floatx4){0.f, 0.f, 0.f, 0.f};

    gemm_bt_core64_db(hp + (size_t)m0 * Hdim, Hdim,
                      Wb + (size_t)n0 * Hdim, Hdim, Hdim, lA, lB, acc);

    const int tid = threadIdx.x, lane = tid & 63, wave = tid >> 6;
    const int wr = wave >> 1, wc = wave & 1;
    const int cl = lane & 15, rh = (lane >> 4) * 4;
    #pragma unroll
    for (int mi = 0; mi < 4; ++mi)
        #pragma unroll
        for (int ni = 0; ni < 4; ++ni)
            #pragma unroll
            for (int j = 0; j < 4; ++j) {
                int r = m0 + wr * 64 + mi * 16 + rh + j;
                int c = n0 + wc * 64 + ni * 16 + cl;
                T[(size_t)r * (Rdim * Hdim) + c] = f2bf(acc[mi][ni][j]);
            }
}

// ------- GEMM3 (N-merged): rel[b,l,m*10+r] = hp_b @ T2_b^T + bbil[r] -------
__global__ __launch_bounds__(256) void k_gemm_rel(
    const unsigned short* __restrict__ hp,
    const unsigned short* __restrict__ T,
    const float* __restrict__ bbil,
    float* __restrict__ rel)
{
    __shared__ unsigned short lA[2 * 128 * 64];
    __shared__ unsigned short lB[2 * 128 * 64];
    int nwg = gridDim.x * gridDim.y * gridDim.z;
    int bid = xcd_swz(blockIdx.x + gridDim.x * (blockIdx.y + gridDim.y * blockIdx.z), nwg);
    const int bx = bid % gridDim.x;
    const int by = (bid / gridDim.x) % gridDim.y;
    const int b  = bid / (gridDim.x * gridDim.y);
    const int m0 = bx * 128;            // l
    const int n0 = by * 128;            // merged (m,r), 0..5120
    floatx4 acc[4][4];
    #pragma unroll
    for (int i = 0; i < 4; ++i)
        #pragma unroll
        for (int j = 0; j < 4; ++j)
            acc[i][j] = (floatx4){0.f, 0.f, 0.f, 0.f};

    const unsigned short* Ab = hp + ((size_t)b * Ldim + m0) * Hdim;
    const unsigned short* Bb = T + (size_t)b * Ldim * (Rdim * Hdim) + (size_t)n0 * Hdim;
    gemm_bt_core64_db(Ab, Hdim, Bb, Hdim, Hdim, lA, lB, acc);

    const int tid = threadIdx.x, lane = tid & 63, wave = tid >> 6;
    const int wr = wave >> 1, wc = wave & 1;
    const int cl = lane & 15, rh = (lane >> 4) * 4;
    #pragma unroll
    for (int mi = 0; mi < 4; ++mi)
        #pragma unroll
        for (int ni = 0; ni < 4; ++ni) {
            int n = n0 + wc * 64 + ni * 16 + cl;
            float bias = bbil[n % Rdim];
            #pragma unroll
            for (int j = 0; j < 4; ++j) {
                int lrow = m0 + wr * 64 + mi * 16 + rh + j;
                rel[((size_t)b * Ldim + lrow) * (Ldim * Rdim) + n] =
                    acc[mi][ni][j] + bias;
            }
        }
}

// ---------------- ent_logits: wave-per-row, 10 dots of length 768 ----------
__global__ __launch_bounds__(256) void k_ent(
    const unsigned short* __restrict__ hp,
    const unsigned short* __restrict__ We,
    const float* __restrict__ bent,
    float* __restrict__ out)
{
    const int gw = (blockIdx.x * blockDim.x + threadIdx.x) >> 6;  // wave id
    const int lane = threadIdx.x & 63;
    if (gw >= Bdim * Ldim) return;
    const unsigned short* row = hp + (size_t)gw * Hdim;
    float hv[12];
    #pragma unroll
    for (int j = 0; j < 12; ++j) hv[j] = bf2f(row[lane + j * 64]);
    #pragma unroll
    for (int e = 0; e < Edim; ++e) {
        const unsigned short* wrow = We + e * Hdim;
        float s = 0.f;
        #pragma unroll
        for (int j = 0; j < 12; ++j) s += hv[j] * bf2f(wrow[lane + j * 64]);
        #pragma unroll
        for (int off = 32; off >= 1; off >>= 1) s += __shfl_xor(s, off);
        if (lane == 0) out[(size_t)gw * Edim + e] = s + bent[e];
    }
}

extern "C" void kernel_launch(void* const* d_in, const int* in_sizes, int n_in,
                              void* d_out, int out_size, void* d_ws, size_t ws_size,
                              hipStream_t stream)
{
    const float* h     = (const float*)d_in[0];
    const float* Wproj = (const float*)d_in[1];
    const float* bproj = (const float*)d_in[2];
    const float* Went  = (const float*)d_in[3];
    const float* bent  = (const float*)d_in[4];
    const float* Wbil  = (const float*)d_in[5];
    const float* bbil  = (const float*)d_in[6];

    float* out_ent = (float*)d_out;
    float* out_rel = (float*)d_out + (size_t)Bdim * Ldim * Edim;

    unsigned short* h_bf  = (unsigned short*)d_ws;
    unsigned short* Wp_bf = h_bf  + (size_t)2048 * Hdim;
    unsigned short* Wb_bf = Wp_bf + (size_t)Hdim * Hdim;
    unsigned short* We_bf = Wb_bf + (size_t)Rdim * Hdim * Hdim;
    unsigned short* hp_bf = We_bf + (size_t)Edim * Hdim;
    unsigned short* T_bf  = hp_bf + (size_t)2048 * Hdim;   // 2048 x 7680

    // single fused conversion launch
    {
        int n0 = 2048 * Hdim / 4;
        int n1 = Hdim * Hdim / 4;
        int n2 = Rdim * Hdim * Hdim / 4;
        int n3 = Edim * Hdim / 4;
        k_cvt4<<<dim3(2048), 256, 0, stream>>>(h, h_bf, n0, Wproj, Wp_bf, n1,
                                               Wbil, Wb_bf, n2, Went, We_bf, n3);
    }

    // GEMM1: hp = relu(h @ Wproj^T + b)   (2048x768) * (768x768)
    k_gemm_proj<<<dim3(2048 / 128, Hdim / 128), 256, 0, stream>>>(h_bf, Wp_bf, bproj, hp_bf);

    // ent logits (needs hp)
    k_ent<<<dim3((Bdim * Ldim * 64) / 256), 256, 0, stream>>>(hp_bf, We_bf, bent, out_ent);

    // GEMM2: T = hp @ Wbil^T   (2048x768) * (768x7680)
    k_gemm_t<<<dim3(2048 / 128, (Rdim * Hdim) / 128), 256, 0, stream>>>(hp_bf, Wb_bf, T_bf);

    // GEMM3: rel (N-merged)  4 batches of (512 x 5120 x 768)
    k_gemm_rel<<<dim3(Ldim / 128, (Ldim * Rdim) / 128, Bdim), 256, 0, stream>>>(hp_bf, T_bf, bbil, out_rel);
}

// Round 5
// 174.494 us; speedup vs baseline: 1.2485x; 1.0450x over previous
//
#include <hip/hip_runtime.h>
#include <stdint.h>

#define Bdim 4
#define Ldim 512
#define Hdim 768
#define Edim 10
#define Rdim 10

typedef __attribute__((ext_vector_type(8))) short short8;
typedef __attribute__((ext_vector_type(4))) float floatx4;

__device__ __forceinline__ unsigned short f2bf(float x) {
    unsigned int u = __float_as_uint(x);
    unsigned int r = (u + 0x7fffu + ((u >> 16) & 1u)) >> 16;
    return (unsigned short)r;
}
__device__ __forceinline__ float bf2f(unsigned short u) {
    return __uint_as_float(((unsigned int)u) << 16);
}

#define GLOAD_LDS16(g, l)                                                      \
    __builtin_amdgcn_global_load_lds(                                          \
        (const __attribute__((address_space(1))) void*)(g),                    \
        (__attribute__((address_space(3))) void*)(l), 16, 0, 0)

// ---------------- fused f32 -> bf16 conversion (4 segments) ----------------
__global__ void k_cvt4(const float* __restrict__ s0, unsigned short* __restrict__ d0, int n0,
                       const float* __restrict__ s1, unsigned short* __restrict__ d1, int n1,
                       const float* __restrict__ s2, unsigned short* __restrict__ d2, int n2,
                       const float* __restrict__ s3, unsigned short* __restrict__ d3, int n3) {
    int total = n0 + n1 + n2 + n3;   // in float4 units
    int i = blockIdx.x * blockDim.x + threadIdx.x;
    int stride = gridDim.x * blockDim.x;
    for (; i < total; i += stride) {
        const float* s; unsigned short* d; int j = i;
        if (j < n0) { s = s0; d = d0; }
        else { j -= n0;
            if (j < n1) { s = s1; d = d1; }
            else { j -= n1;
                if (j < n2) { s = s2; d = d2; }
                else { j -= n2; s = s3; d = d3; }
            }
        }
        float4 v = reinterpret_cast<const float4*>(s)[j];
        ushort4 o;
        o.x = f2bf(v.x); o.y = f2bf(v.y); o.z = f2bf(v.z); o.w = f2bf(v.w);
        reinterpret_cast<ushort4*>(d)[j] = o;
    }
}

// bijective XCD remap of a linear block id (all our grids are %8==0)
__device__ __forceinline__ int xcd_swz(int bid, int nwg) {
    int cpx = nwg >> 3;
    return (bid & 7) * cpx + (bid >> 3);
}

// ===================== 128^2 core (kept for k_gemm_proj) =====================
__device__ __forceinline__ void gemm_bt_core64_db(
    const unsigned short* __restrict__ A, int lda,
    const unsigned short* __restrict__ Bm, int ldb,
    int K,
    unsigned short* lA, unsigned short* lB,
    floatx4 acc[4][4])
{
    const int tid  = threadIdx.x;
    const int lane = tid & 63;
    const int wave = tid >> 6;
    const int wr = wave >> 1;
    const int wc = wave & 1;

    const int srow   = tid >> 3;
    const int schunk = (tid & 7) ^ (srow & 7);
    const int skk    = schunk << 3;

    const int frow = lane & 15;
    const int fs   = lane >> 4;

    #pragma unroll
    for (int i = 0; i < 4; ++i) {
        GLOAD_LDS16(A  + (size_t)(srow + 32 * i) * lda + skk,
                    lA + (tid + 256 * i) * 8);
        GLOAD_LDS16(Bm + (size_t)(srow + 32 * i) * ldb + skk,
                    lB + (tid + 256 * i) * 8);
    }
    __syncthreads();

    const int nt = K >> 6;
    int buf = 0;
    for (int kt = 0; kt < nt; ++kt) {
        if (kt + 1 < nt) {
            const int k0n = (kt + 1) << 6;
            unsigned short* dA = lA + (buf ^ 1) * 8192;
            unsigned short* dB = lB + (buf ^ 1) * 8192;
            #pragma unroll
            for (int i = 0; i < 4; ++i) {
                GLOAD_LDS16(A  + (size_t)(srow + 32 * i) * lda + k0n + skk,
                            dA + (tid + 256 * i) * 8);
                GLOAD_LDS16(Bm + (size_t)(srow + 32 * i) * ldb + k0n + skk,
                            dB + (tid + 256 * i) * 8);
            }
        }
        const unsigned short* sA = lA + buf * 8192;
        const unsigned short* sB = lB + buf * 8192;
        #pragma unroll
        for (int h = 0; h < 2; ++h) {
            short8 af[4], bfr[4];
            #pragma unroll
            for (int mi = 0; mi < 4; ++mi) {
                int row  = wr * 64 + mi * 16 + frow;
                int slot = (fs + 4 * h) ^ (row & 7);
                af[mi] = *reinterpret_cast<const short8*>(sA + row * 64 + slot * 8);
            }
            #pragma unroll
            for (int ni = 0; ni < 4; ++ni) {
                int row  = wc * 64 + ni * 16 + frow;
                int slot = (fs + 4 * h) ^ (row & 7);
                bfr[ni] = *reinterpret_cast<const short8*>(sB + row * 64 + slot * 8);
            }
            #pragma unroll
            for (int mi = 0; mi < 4; ++mi)
                #pragma unroll
                for (int ni = 0; ni < 4; ++ni)
                    acc[mi][ni] = __builtin_amdgcn_mfma_f32_16x16x32_bf16(
                        af[mi], bfr[ni], acc[mi][ni], 0, 0, 0);
        }
        __syncthreads();
        buf ^= 1;
    }
}

// ============ 256^2 core: 512 threads, 8 waves (2M x 4N), BK=64 =============
// LDS: 2 buf x [256][64] bf16 per matrix (lA,lB each 64KB -> 128KB/block).
// Per-wave output 128x64 (acc[8][4]). Same XOR swizzle (slot ^= row&7):
// linear LDS dest + pre-swizzled global source + swizzled ds_read (rule #21).
__device__ __forceinline__ void gemm_bt_core256_db(
    const unsigned short* __restrict__ A, int lda,
    const unsigned short* __restrict__ Bm, int ldb,
    int K,
    unsigned short* lA, unsigned short* lB,
    floatx4 acc[8][4])
{
    const int tid  = threadIdx.x;       // 0..511
    const int lane = tid & 63;
    const int wave = tid >> 6;          // 0..7
    const int wr = wave >> 2;           // 0..1  (M)
    const int wc = wave & 3;            // 0..3  (N)

    // staging: 512 threads x 16B chunk; 8 chunks/row -> 64 rows per instr
    const int srow   = tid >> 3;                  // 0..63
    const int schunk = (tid & 7) ^ (srow & 7);    // pre-swizzled k-chunk
    const int skk    = schunk << 3;

    const int frow = lane & 15;
    const int fs   = lane >> 4;                   // 0..3

    // prologue: stage K-tile 0 into buffer 0
    #pragma unroll
    for (int i = 0; i < 4; ++i) {
        GLOAD_LDS16(A  + (size_t)(srow + 64 * i) * lda + skk,
                    lA + (tid + 512 * i) * 8);
        GLOAD_LDS16(Bm + (size_t)(srow + 64 * i) * ldb + skk,
                    lB + (tid + 512 * i) * 8);
    }
    __syncthreads();

    const int nt = K >> 6;
    int buf = 0;
    for (int kt = 0; kt < nt; ++kt) {
        if (kt + 1 < nt) {
            const int k0n = (kt + 1) << 6;
            unsigned short* dA = lA + (buf ^ 1) * 16384;
            unsigned short* dB = lB + (buf ^ 1) * 16384;
            #pragma unroll
            for (int i = 0; i < 4; ++i) {
                GLOAD_LDS16(A  + (size_t)(srow + 64 * i) * lda + k0n + skk,
                            dA + (tid + 512 * i) * 8);
                GLOAD_LDS16(Bm + (size_t)(srow + 64 * i) * ldb + k0n + skk,
                            dB + (tid + 512 * i) * 8);
            }
        }
        const unsigned short* sA = lA + buf * 16384;
        const unsigned short* sB = lB + buf * 16384;
        #pragma unroll
        for (int h = 0; h < 2; ++h) {
            short8 bfr[4];
            #pragma unroll
            for (int ni = 0; ni < 4; ++ni) {
                int row  = wc * 64 + ni * 16 + frow;
                int slot = (fs + 4 * h) ^ (row & 7);
                bfr[ni] = *reinterpret_cast<const short8*>(sB + row * 64 + slot * 8);
            }
            #pragma unroll
            for (int mi = 0; mi < 8; ++mi) {
                int row  = wr * 128 + mi * 16 + frow;
                int slot = (fs + 4 * h) ^ (row & 7);
                short8 af = *reinterpret_cast<const short8*>(sA + row * 64 + slot * 8);
                #pragma unroll
                for (int ni = 0; ni < 4; ++ni)
                    acc[mi][ni] = __builtin_amdgcn_mfma_f32_16x16x32_bf16(
                        af, bfr[ni], acc[mi][ni], 0, 0, 0);
            }
        }
        __syncthreads();
        buf ^= 1;
    }
}

// ---------------- GEMM1: hp = relu(h @ Wproj^T + b) -> bf16 (128^2) --------
__global__ __launch_bounds__(256) void k_gemm_proj(
    const unsigned short* __restrict__ hA,
    const unsigned short* __restrict__ Wp,
    const float* __restrict__ bproj,
    unsigned short* __restrict__ hp)
{
    __shared__ unsigned short lA[2 * 128 * 64];
    __shared__ unsigned short lB[2 * 128 * 64];
    int bid = xcd_swz(blockIdx.x + gridDim.x * blockIdx.y, gridDim.x * gridDim.y);
    const int m0 = (bid % gridDim.x) * 128;
    const int n0 = (bid / gridDim.x) * 128;
    floatx4 acc[4][4];
    #pragma unroll
    for (int i = 0; i < 4; ++i)
        #pragma unroll
        for (int j = 0; j < 4; ++j)
            acc[i][j] = (floatx4){0.f, 0.f, 0.f, 0.f};

    gemm_bt_core64_db(hA + (size_t)m0 * Hdim, Hdim,
                      Wp + (size_t)n0 * Hdim, Hdim, Hdim, lA, lB, acc);

    const int tid = threadIdx.x, lane = tid & 63, wave = tid >> 6;
    const int wr = wave >> 1, wc = wave & 1;
    const int cl = lane & 15, rh = (lane >> 4) * 4;
    #pragma unroll
    for (int mi = 0; mi < 4; ++mi)
        #pragma unroll
        for (int ni = 0; ni < 4; ++ni)
            #pragma unroll
            for (int j = 0; j < 4; ++j) {
                int r = m0 + wr * 64 + mi * 16 + rh + j;
                int c = n0 + wc * 64 + ni * 16 + cl;
                float v = acc[mi][ni][j] + bproj[c];
                hp[(size_t)r * Hdim + c] = f2bf(fmaxf(v, 0.0f));
            }
}

// -------- GEMM2 (256^2): T[m, r*768+h] = hp @ Wbil^T -> bf16 ---------------
__global__ __launch_bounds__(512, 1) void k_gemm_t(
    const unsigned short* __restrict__ hp,
    const unsigned short* __restrict__ Wb,
    unsigned short* __restrict__ T)
{
    __shared__ unsigned short lA[2 * 256 * 64];
    __shared__ unsigned short lB[2 * 256 * 64];
    int bid = xcd_swz(blockIdx.x + gridDim.x * blockIdx.y, gridDim.x * gridDim.y);
    const int m0 = (bid % gridDim.x) * 256;
    const int n0 = (bid / gridDim.x) * 256;   // over R*H = 7680
    floatx4 acc[8][4];
    #pragma unroll
    for (int i = 0; i < 8; ++i)
        #pragma unroll
        for (int j = 0; j < 4; ++j)
            acc[i][j] = (floatx4){0.f, 0.f, 0.f, 0.f};

    gemm_bt_core256_db(hp + (size_t)m0 * Hdim, Hdim,
                       Wb + (size_t)n0 * Hdim, Hdim, Hdim, lA, lB, acc);

    const int tid = threadIdx.x, lane = tid & 63, wave = tid >> 6;
    const int wr = wave >> 2, wc = wave & 3;
    const int cl = lane & 15, rh = (lane >> 4) * 4;
    #pragma unroll
    for (int mi = 0; mi < 8; ++mi)
        #pragma unroll
        for (int ni = 0; ni < 4; ++ni)
            #pragma unroll
            for (int j = 0; j < 4; ++j) {
                int r = m0 + wr * 128 + mi * 16 + rh + j;
                int c = n0 + wc * 64 + ni * 16 + cl;
                T[(size_t)r * (Rdim * Hdim) + c] = f2bf(acc[mi][ni][j]);
            }
}

// ------ GEMM3 (256^2, N-merged): rel[grow, m*10+r] = hp @ T2_b^T + b -------
// grow = b*512 + l runs 0..2047 contiguously; M-tiles of 256 stay within one
// b (512 % 256 == 0), so b = m0 >> 9. Output [2048][5120] fp32, coalesced.
__global__ __launch_bounds__(512, 1) void k_gemm_rel(
    const unsigned short* __restrict__ hp,
    const unsigned short* __restrict__ T,
    const float* __restrict__ bbil,
    float* __restrict__ rel)
{
    __shared__ unsigned short lA[2 * 256 * 64];
    __shared__ unsigned short lB[2 * 256 * 64];
    int bid = xcd_swz(blockIdx.x + gridDim.x * blockIdx.y, gridDim.x * gridDim.y);
    const int m0 = (bid % gridDim.x) * 256;   // global row over 2048
    const int n0 = (bid / gridDim.x) * 256;   // merged (m,r) over 5120
    const int b  = m0 >> 9;
    floatx4 acc[8][4];
    #pragma unroll
    for (int i = 0; i < 8; ++i)
        #pragma unroll
        for (int j = 0; j < 4; ++j)
            acc[i][j] = (floatx4){0.f, 0.f, 0.f, 0.f};

    const unsigned short* Ab = hp + (size_t)m0 * Hdim;
    const unsigned short* Bb = T + (size_t)b * Ldim * (Rdim * Hdim) + (size_t)n0 * Hdim;
    gemm_bt_core256_db(Ab, Hdim, Bb, Hdim, Hdim, lA, lB, acc);

    const int tid = threadIdx.x, lane = tid & 63, wave = tid >> 6;
    const int wr = wave >> 2, wc = wave & 3;
    const int cl = lane & 15, rh = (lane >> 4) * 4;
    #pragma unroll
    for (int mi = 0; mi < 8; ++mi)
        #pragma unroll
        for (int ni = 0; ni < 4; ++ni) {
            int n = n0 + wc * 64 + ni * 16 + cl;
            float bias = bbil[n % Rdim];
            #pragma unroll
            for (int j = 0; j < 4; ++j) {
                int grow = m0 + wr * 128 + mi * 16 + rh + j;
                rel[(size_t)grow * (Ldim * Rdim) + n] = acc[mi][ni][j] + bias;
            }
        }
}

// ---------------- ent_logits: wave-per-row, 10 dots of length 768 ----------
__global__ __launch_bounds__(256) void k_ent(
    const unsigned short* __restrict__ hp,
    const unsigned short* __restrict__ We,
    const float* __restrict__ bent,
    float* __restrict__ out)
{
    const int gw = (blockIdx.x * blockDim.x + threadIdx.x) >> 6;  // wave id
    const int lane = threadIdx.x & 63;
    if (gw >= Bdim * Ldim) return;
    const unsigned short* row = hp + (size_t)gw * Hdim;
    float hv[12];
    #pragma unroll
    for (int j = 0; j < 12; ++j) hv[j] = bf2f(row[lane + j * 64]);
    #pragma unroll
    for (int e = 0; e < Edim; ++e) {
        const unsigned short* wrow = We + e * Hdim;
        float s = 0.f;
        #pragma unroll
        for (int j = 0; j < 12; ++j) s += hv[j] * bf2f(wrow[lane + j * 64]);
        #pragma unroll
        for (int off = 32; off >= 1; off >>= 1) s += __shfl_xor(s, off);
        if (lane == 0) out[(size_t)gw * Edim + e] = s + bent[e];
    }
}

extern "C" void kernel_launch(void* const* d_in, const int* in_sizes, int n_in,
                              void* d_out, int out_size, void* d_ws, size_t ws_size,
                              hipStream_t stream)
{
    const float* h     = (const float*)d_in[0];
    const float* Wproj = (const float*)d_in[1];
    const float* bproj = (const float*)d_in[2];
    const float* Went  = (const float*)d_in[3];
    const float* bent  = (const float*)d_in[4];
    const float* Wbil  = (const float*)d_in[5];
    const float* bbil  = (const float*)d_in[6];

    float* out_ent = (float*)d_out;
    float* out_rel = (float*)d_out + (size_t)Bdim * Ldim * Edim;

    unsigned short* h_bf  = (unsigned short*)d_ws;
    unsigned short* Wp_bf = h_bf  + (size_t)2048 * Hdim;
    unsigned short* Wb_bf = Wp_bf + (size_t)Hdim * Hdim;
    unsigned short* We_bf = Wb_bf + (size_t)Rdim * Hdim * Hdim;
    unsigned short* hp_bf = We_bf + (size_t)Edim * Hdim;
    unsigned short* T_bf  = hp_bf + (size_t)2048 * Hdim;   // 2048 x 7680

    // single fused conversion launch
    {
        int n0 = 2048 * Hdim / 4;
        int n1 = Hdim * Hdim / 4;
        int n2 = Rdim * Hdim * Hdim / 4;
        int n3 = Edim * Hdim / 4;
        k_cvt4<<<dim3(2048), 256, 0, stream>>>(h, h_bf, n0, Wproj, Wp_bf, n1,
                                               Wbil, Wb_bf, n2, Went, We_bf, n3);
    }

    // GEMM1: hp = relu(h @ Wproj^T + b)   (2048x768) * (768x768), 128^2 tiles
    k_gemm_proj<<<dim3(2048 / 128, Hdim / 128), 256, 0, stream>>>(h_bf, Wp_bf, bproj, hp_bf);

    // ent logits (needs hp)
    k_ent<<<dim3((Bdim * Ldim * 64) / 256), 256, 0, stream>>>(hp_bf, We_bf, bent, out_ent);

    // GEMM2: T = hp @ Wbil^T   (2048x768)*(768x7680), 256^2 tiles, 240 blocks
    k_gemm_t<<<dim3(2048 / 256, (Rdim * Hdim) / 256), 512, 0, stream>>>(hp_bf, Wb_bf, T_bf);

    // GEMM3: rel  (2048 x 5120 x 768 with per-256-row-tile B), 160 blocks
    k_gemm_rel<<<dim3(2048 / 256, (Ldim * Rdim) / 256), 512, 0, stream>>>(hp_bf, T_bf, bbil, out_rel);
}